// Round 4
// baseline (183.322 us; speedup 1.0000x reference)
//
#include <hip/hip_runtime.h>
#include <hip/hip_bf16.h>

// AdjGAT: V=20000, D=256, K=16, O=128, H=4.
// Math restructure: attn[h,v] = x[v] . (W_h a_h)  (no big GEMM needed for logits)
//                   out[v]    = relu( (1/H) sum_h (sum_k c[h,v,k] x[nbr]) . W_h + bbar )
// so we gather x rows (shared across heads) instead of t rows (per-head): half the
// random traffic, and t never exists.
// Pipeline:
//   K0a prep_w:  W fp32 -> Wt_hi/Wt_lo [h][o][d] fp16 (split, transposed)
//   K0b wtilde:  wt[h][d] = sum_o W[h][d][o]*a[h][o]   (fp32, tiny)
//   K0c xsplit:  xh[v][d] fp16 = x; attn4[v][h] = x[v].wt[h] (fp32, fused)
//   K1  gat:     per 16-node block: softmax coefs (width-16 shuffles) ->
//                y[h,node,:] = sum_k c*xh[nbr] (fp32 regs) -> hi/lo fp16 LDS ->
//                3-term fp16 MFMA vs Wt -> mean heads + bbar + relu -> out.
// ws: attn4 0.32MB | xh 10.24MB | Wt 0.5MB | wt 4KB   (~11.1MB total)

#define V_N 20000
#define D_N 256
#define K_N 16
#define O_N 128
#define H_N 4
#define NEG_INF -1e9f
#define TM 16            // nodes per block in K1; V = 1250 * 16 exactly
#define LDY 264          // padded LDS d-stride (fp16 elems): 528B -> bank step 4

typedef _Float16 f16x8 __attribute__((ext_vector_type(8)));
typedef _Float16 f16x4 __attribute__((ext_vector_type(4)));
typedef float    f32x4 __attribute__((ext_vector_type(4)));

// ---------------- K0a: split + transpose W -> [h][o][d] fp16 hi/lo ----------------
__global__ __launch_bounds__(256) void prep_w_kernel(
    const float* __restrict__ W, _Float16* __restrict__ Wt_hi,
    _Float16* __restrict__ Wt_lo)
{
    const int idx = blockIdx.x * 256 + threadIdx.x;   // [h][o][d] order
    const int d    = idx & (D_N - 1);
    const int rest = idx >> 8;
    const int o    = rest & (O_N - 1);
    const int h    = rest >> 7;
    const float f  = W[((size_t)(h * D_N + d)) * O_N + o];
    const _Float16 hi = (_Float16)f;
    Wt_hi[idx] = hi;
    Wt_lo[idx] = (_Float16)(f - (float)hi);
}

// ---------------- K0b: wt[h][d] = sum_o W[h][d][o] * a[h][o] ----------------
__global__ __launch_bounds__(256) void wtilde_kernel(
    const float* __restrict__ W, const float* __restrict__ a,
    float* __restrict__ wt)
{
    const int h = blockIdx.x;          // 0..3
    const int d = threadIdx.x;         // 0..255
    const float* Wrow = W + ((size_t)h * D_N + d) * O_N;
    const float* ah   = a + h * O_N;
    float s = 0.f;
    #pragma unroll
    for (int o = 0; o < O_N; o += 4) {
        const float4 wv = *(const float4*)&Wrow[o];
        const float4 av = *(const float4*)&ah[o];
        s = fmaf(wv.x, av.x, s); s = fmaf(wv.y, av.y, s);
        s = fmaf(wv.z, av.z, s); s = fmaf(wv.w, av.w, s);
    }
    wt[h * D_N + d] = s;
}

// ---------------- K0c: x -> fp16 copy + fused attn logits ----------------
// 5000 blocks x 256 thr; wave = one row v. attn4 layout [v][h] (float4/node).
__global__ __launch_bounds__(256) void xsplit_attn_kernel(
    const float* __restrict__ x, const float* __restrict__ wt,
    _Float16* __restrict__ xh, float* __restrict__ attn4)
{
    const int wid  = threadIdx.x >> 6;
    const int lane = threadIdx.x & 63;
    const int v    = blockIdx.x * 4 + wid;

    const float4 p = *(const float4*)&x[(size_t)v * D_N + lane * 4];
    f16x4 hv = { (_Float16)p.x, (_Float16)p.y, (_Float16)p.z, (_Float16)p.w };
    *(f16x4*)&xh[(size_t)v * D_N + lane * 4] = hv;

    float s[H_N];
    #pragma unroll
    for (int h = 0; h < H_N; ++h) {
        const float4 w = *(const float4*)&wt[h * D_N + lane * 4];
        float t = fmaf(p.x, w.x, 0.f);
        t = fmaf(p.y, w.y, t); t = fmaf(p.z, w.z, t); t = fmaf(p.w, w.w, t);
        s[h] = t;
    }
    #pragma unroll
    for (int h = 0; h < H_N; ++h)
        #pragma unroll
        for (int dd = 32; dd >= 1; dd >>= 1)
            s[h] += __shfl_xor(s[h], dd);
    if (lane == 0)
        *(float4*)&attn4[(size_t)v * 4] = make_float4(s[0], s[1], s[2], s[3]);
}

// ---------------- K1: fused softmax + gather + GEMM ----------------
// 1250 blocks x 256 thr (4 waves). Phase 1: thread=(node,k) softmax.
// Phase 2: wave owns 4 nodes; lane owns 4 d-channels; y fp32 in regs.
// Phase 3: wave owns 32 output cols; A=y from LDS, B=Wt from global (L2-hot).
__global__ __launch_bounds__(256, 2) void gat_kernel(
    const _Float16* __restrict__ xh, const float* __restrict__ attn4,
    const _Float16* __restrict__ Wt_hi, const _Float16* __restrict__ Wt_lo,
    const float* __restrict__ b, const int* __restrict__ adj,
    const int* __restrict__ mask_p, float* __restrict__ out)
{
    const int v0  = blockIdx.x * TM;
    const int tid = threadIdx.x;

    __shared__ float    coefs_s[TM][K_N][H_N];   // [node][k][h], float4-readable
    __shared__ int      sidx_s[TM][K_N];
    __shared__ _Float16 yhi[H_N * TM * LDY];
    __shared__ _Float16 ylo[H_N * TM * LDY];

    // ---- phase 1: per-(node,k) softmax over K, all heads ----
    {
        const int node = tid >> 4;
        const int k    = tid & 15;
        const int mask = mask_p[0];
        const int idx  = adj[(v0 + node) * K_N + k];
        const bool pad = (idx >= mask);
        const int safe = pad ? 0 : idx;
        const float4 av = *(const float4*)&attn4[(size_t)safe * 4];
        float lg[H_N] = { pad ? NEG_INF : av.x, pad ? NEG_INF : av.y,
                          pad ? NEG_INF : av.z, pad ? NEG_INF : av.w };
        float c[H_N];
        #pragma unroll
        for (int h = 0; h < H_N; ++h) {
            float m = lg[h];
            #pragma unroll
            for (int s = 8; s >= 1; s >>= 1)
                m = fmaxf(m, __shfl_xor(m, s, 16));
            const float e = pad ? 0.f : __expf(lg[h] - m);
            float sum = e;
            #pragma unroll
            for (int s = 8; s >= 1; s >>= 1)
                sum += __shfl_xor(sum, s, 16);
            // pad coef 0 == ref (exp(-1e9-m)==0); all-pad row -> y=0, out=relu(bbar)
            c[h] = pad ? 0.f : e / sum;
        }
        *(float4*)&coefs_s[node][k][0] = make_float4(c[0], c[1], c[2], c[3]);
        if ((tid & 15) == k) sidx_s[node][k] = safe;   // always true; keep simple
    }
    __syncthreads();

    const int wid  = tid >> 6;
    const int lane = tid & 63;

    // ---- phase 2: y[h][node][d] = sum_k c * xh[nbr][d]; wave owns 4 nodes ----
    {
        float y[4][H_N][4];   // [local node][head][d sub]
        #pragma unroll
        for (int nl = 0; nl < 4; ++nl)
            #pragma unroll
            for (int h = 0; h < H_N; ++h)
                #pragma unroll
                for (int j = 0; j < 4; ++j) y[nl][h][j] = 0.f;

        #pragma unroll 4
        for (int k = 0; k < K_N; ++k) {
            #pragma unroll
            for (int nl = 0; nl < 4; ++nl) {
                const int node = wid * 4 + nl;
                const int si   = sidx_s[node][k];
                const f16x4 r  = *(const f16x4*)&xh[(size_t)si * D_N + lane * 4];
                const float4 c = *(const float4*)&coefs_s[node][k][0];
                const float f0 = (float)r[0], f1 = (float)r[1],
                            f2 = (float)r[2], f3 = (float)r[3];
                const float ch[4] = { c.x, c.y, c.z, c.w };
                #pragma unroll
                for (int h = 0; h < H_N; ++h) {
                    y[nl][h][0] = fmaf(ch[h], f0, y[nl][h][0]);
                    y[nl][h][1] = fmaf(ch[h], f1, y[nl][h][1]);
                    y[nl][h][2] = fmaf(ch[h], f2, y[nl][h][2]);
                    y[nl][h][3] = fmaf(ch[h], f3, y[nl][h][3]);
                }
            }
        }
        // split to fp16 hi/lo in LDS
        #pragma unroll
        for (int nl = 0; nl < 4; ++nl) {
            const int node = wid * 4 + nl;
            #pragma unroll
            for (int h = 0; h < H_N; ++h) {
                f16x4 hi, lo;
                #pragma unroll
                for (int j = 0; j < 4; ++j) {
                    const float val = y[nl][h][j];
                    const _Float16 hh = (_Float16)val;
                    hi[j] = hh;
                    lo[j] = (_Float16)(val - (float)hh);
                }
                const int off = (h * TM + node) * LDY + lane * 4;
                *(f16x4*)&yhi[off] = hi;
                *(f16x4*)&ylo[off] = lo;
            }
        }
    }
    __syncthreads();

    // ---- phase 3: out = (1/H) sum_h y_h . W_h  (3-term split fp16 MFMA) ----
    {
        const int lo4 = lane & 15;
        const int q   = lane >> 4;
        f32x4 acc[2];
        acc[0] = (f32x4){0.f, 0.f, 0.f, 0.f};
        acc[1] = (f32x4){0.f, 0.f, 0.f, 0.f};

        #pragma unroll
        for (int h = 0; h < H_N; ++h) {
            #pragma unroll
            for (int kc = 0; kc < D_N; kc += 32) {
                const int aoff = (h * TM + lo4) * LDY + kc + q * 8;
                const f16x8 ah = *(const f16x8*)&yhi[aoff];
                const f16x8 al = *(const f16x8*)&ylo[aoff];
                #pragma unroll
                for (int nt = 0; nt < 2; ++nt) {
                    const int col = wid * 32 + nt * 16 + lo4;
                    const size_t boff = ((size_t)(h * O_N + col) << 8) + kc + q * 8;
                    const f16x8 bh = *(const f16x8*)&Wt_hi[boff];
                    const f16x8 bl = *(const f16x8*)&Wt_lo[boff];
                    acc[nt] = __builtin_amdgcn_mfma_f32_16x16x32_f16(
                        ah, bh, acc[nt], 0, 0, 0);
                    acc[nt] = __builtin_amdgcn_mfma_f32_16x16x32_f16(
                        al, bh, acc[nt], 0, 0, 0);
                    acc[nt] = __builtin_amdgcn_mfma_f32_16x16x32_f16(
                        ah, bl, acc[nt], 0, 0, 0);
                }
            }
        }
        // epilogue: mean heads + mean bias + relu
        #pragma unroll
        for (int nt = 0; nt < 2; ++nt) {
            const int col = wid * 32 + nt * 16 + lo4;
            const float bb = 0.25f * (b[col] + b[O_N + col] +
                                      b[2 * O_N + col] + b[3 * O_N + col]);
            #pragma unroll
            for (int r = 0; r < 4; ++r) {
                const int node = q * 4 + r;          // C row = quad*4 + reg
                const float val = acc[nt][r] * 0.25f + bb;
                out[(size_t)(v0 + node) * O_N + col] = fmaxf(val, 0.f);
            }
        }
    }
}

extern "C" void kernel_launch(void* const* d_in, const int* in_sizes, int n_in,
                              void* d_out, int out_size, void* d_ws, size_t ws_size,
                              hipStream_t stream) {
    const float* x      = (const float*)d_in[0];
    const float* W      = (const float*)d_in[1];
    const float* a      = (const float*)d_in[2];
    const float* b      = (const float*)d_in[3];
    const int*   adj    = (const int*)d_in[4];
    const int*   mask_p = (const int*)d_in[5];
    float*       out    = (float*)d_out;

    // ws layout (bytes)
    char* p = (char*)d_ws;
    float*    attn4 = (float*)p;                     //    320,000
    _Float16* xh    = (_Float16*)(p + 320000);       // 10,240,000
    _Float16* Wthi  = (_Float16*)(p + 10560000);     //    262,144
    _Float16* Wtlo  = (_Float16*)(p + 10822144);     //    262,144
    float*    wt    = (float*)(p + 11084288);        //      4,096  (end ~11.1MB)

    prep_w_kernel<<<(H_N * O_N * D_N) / 256, 256, 0, stream>>>(W, Wthi, Wtlo);
    wtilde_kernel<<<H_N, 256, 0, stream>>>(W, a, wt);
    xsplit_attn_kernel<<<V_N / 4, 256, 0, stream>>>(x, wt, xh, attn4);
    gat_kernel<<<V_N / TM, 256, 0, stream>>>(xh, attn4, Wthi, Wtlo, b, adj,
                                             mask_p, out);
}

// Round 5
// 149.622 us; speedup vs baseline: 1.2252x; 1.2252x over previous
//
#include <hip/hip_runtime.h>

// AdjGAT: V=20000, D=256, K=16, O=128, H=4.
// Math: attn[h,v] = x[v].(W_h a_h);  out[v] = relu( (1/H) [ sum_h (sum_k c_hk x[nbr_k]) . W_h + sum_h b_h ] )
// Gather x rows (head-independent indices) instead of per-head t rows.
// Pipeline:
//   K0a prep_w:  W fp32 [h][d][o] -> Wt fp16 [h][o][d]  (single precision)
//   K0b wtilde:  wt[h][d] = sum_o W[h][d][o]*a[h][o]    (fp32, tiny)
//   K0c xsplit:  xh = fp16(x); attn4[v][h] = x[v].wt[h] (fused)
//   K1  gat:     16 nodes/block, 4 waves. Phase1: softmax coefs (width-16
//                shuffles). Phase2: wave w gathers channel slice [w*64,w*64+64)
//                for all 16 nodes, accumulating y in fp32 regs laid out EXACTLY
//                as MFMA A-fragments (lane = node + 16*(chan_grp)) -> no LDS
//                round-trip, no bank conflicts. Phase3: 2 single-term fp16
//                MFMAs per (h, col-tile) vs L2-resident Wt; cross-wave C
//                reduction in LDS; mean heads + bias + relu.
// ws: attn4 0.32MB | xh 10.24MB | Wt 0.26MB | wt 4KB  (~10.8MB)

#define V_N 20000
#define D_N 256
#define K_N 16
#define O_N 128
#define H_N 4
#define NEG_INF -1e9f
#define TM 16            // nodes per block; V = 1250 * 16
#define CSTR 132         // cred col stride (dwords), breaks power-of-2 banks

typedef _Float16 f16x8 __attribute__((ext_vector_type(8)));
typedef _Float16 f16x4 __attribute__((ext_vector_type(4)));
typedef float    f32x4 __attribute__((ext_vector_type(4)));

// ---------------- K0a: W -> Wt fp16 [h][o][d] ----------------
__global__ __launch_bounds__(256) void prep_w_kernel(
    const float* __restrict__ W, _Float16* __restrict__ Wt)
{
    const int idx = blockIdx.x * 256 + threadIdx.x;   // [h][o][d] order
    const int d    = idx & (D_N - 1);
    const int rest = idx >> 8;
    const int o    = rest & (O_N - 1);
    const int h    = rest >> 7;
    Wt[idx] = (_Float16)W[((size_t)(h * D_N + d)) * O_N + o];
}

// ---------------- K0b: wt[h][d] = sum_o W[h][d][o] * a[h][o] ----------------
__global__ __launch_bounds__(256) void wtilde_kernel(
    const float* __restrict__ W, const float* __restrict__ a,
    float* __restrict__ wt)
{
    const int h = blockIdx.x;
    const int d = threadIdx.x;
    const float* Wrow = W + ((size_t)h * D_N + d) * O_N;
    const float* ah   = a + h * O_N;
    float s = 0.f;
    #pragma unroll
    for (int o = 0; o < O_N; o += 4) {
        const float4 wv = *(const float4*)&Wrow[o];
        const float4 av = *(const float4*)&ah[o];
        s = fmaf(wv.x, av.x, s); s = fmaf(wv.y, av.y, s);
        s = fmaf(wv.z, av.z, s); s = fmaf(wv.w, av.w, s);
    }
    wt[h * D_N + d] = s;
}

// ---------------- K0c: x -> fp16 copy + fused attn logits ----------------
__global__ __launch_bounds__(256) void xsplit_attn_kernel(
    const float* __restrict__ x, const float* __restrict__ wt,
    _Float16* __restrict__ xh, float* __restrict__ attn4)
{
    const int wid  = threadIdx.x >> 6;
    const int lane = threadIdx.x & 63;
    const int v    = blockIdx.x * 4 + wid;

    const float4 p = *(const float4*)&x[(size_t)v * D_N + lane * 4];
    f16x4 hv = { (_Float16)p.x, (_Float16)p.y, (_Float16)p.z, (_Float16)p.w };
    *(f16x4*)&xh[(size_t)v * D_N + lane * 4] = hv;

    float s[H_N];
    #pragma unroll
    for (int h = 0; h < H_N; ++h) {
        const float4 w = *(const float4*)&wt[h * D_N + lane * 4];
        float t = fmaf(p.x, w.x, 0.f);
        t = fmaf(p.y, w.y, t); t = fmaf(p.z, w.z, t); t = fmaf(p.w, w.w, t);
        s[h] = t;
    }
    #pragma unroll
    for (int h = 0; h < H_N; ++h)
        #pragma unroll
        for (int dd = 32; dd >= 1; dd >>= 1)
            s[h] += __shfl_xor(s[h], dd);
    if (lane == 0)
        *(float4*)&attn4[(size_t)v * 4] = make_float4(s[0], s[1], s[2], s[3]);
}

// ---------------- K1: fused softmax + gather + single-term fp16 MFMA --------
__global__ __launch_bounds__(256, 4) void gat_kernel(
    const _Float16* __restrict__ xh, const float* __restrict__ attn4,
    const _Float16* __restrict__ Wt, const float* __restrict__ b,
    const int* __restrict__ adj, const int* __restrict__ mask_p,
    float* __restrict__ out)
{
    const int v0  = blockIdx.x * TM;
    const int tid = threadIdx.x;

    __shared__ int   sidx_s[TM][17];          // padded: phase2 reads broadcast-free
    __shared__ float coefs_s[K_N][17][H_N];   // [k][node(+pad)][h], float4 per node
    __shared__ float cred[4][TM][CSTR];       // per-wave C partials

    // ---- phase 1: softmax coefs, thread = (node, k) ----
    {
        const int node = tid >> 4;
        const int k    = tid & 15;
        const int mask = mask_p[0];
        const int idx  = adj[(v0 + node) * K_N + k];
        const bool pad = (idx >= mask);
        const int safe = pad ? 0 : idx;
        const float4 av = *(const float4*)&attn4[(size_t)safe * 4];
        const float lg[H_N] = { pad ? NEG_INF : av.x, pad ? NEG_INF : av.y,
                                pad ? NEG_INF : av.z, pad ? NEG_INF : av.w };
        float c[H_N];
        #pragma unroll
        for (int h = 0; h < H_N; ++h) {
            float m = lg[h];
            #pragma unroll
            for (int s = 8; s >= 1; s >>= 1)
                m = fmaxf(m, __shfl_xor(m, s, 16));
            const float e = pad ? 0.f : __expf(lg[h] - m);
            float sum = e;
            #pragma unroll
            for (int s = 8; s >= 1; s >>= 1)
                sum += __shfl_xor(sum, s, 16);
            // pad coef 0 == ref (exp(-1e9-m)==0); all-pad row -> y=0 -> relu(bbar)
            c[h] = pad ? 0.f : e / sum;
        }
        *(float4*)&coefs_s[k][node][0] = make_float4(c[0], c[1], c[2], c[3]);
        sidx_s[node][k] = safe;
    }
    __syncthreads();

    const int wid  = tid >> 6;
    const int lane = tid & 63;
    const int m    = lane & 15;           // node (A-frag row)
    const int q    = lane >> 4;           // channel group (A-frag k-group)

    // wave wid owns channels [wid*64, wid*64+64); lane holds 8+8 channels:
    //   tile0: kc = wid*64,    channels wid*64 + q*8 + j
    //   tile1: kc = wid*64+32, channels wid*64 + 32 + q*8 + j
    const _Float16* xbase = xh + wid * 64 + q * 8;

    float y0[H_N][8], y1[H_N][8];
    #pragma unroll
    for (int h = 0; h < H_N; ++h)
        #pragma unroll
        for (int j = 0; j < 8; ++j) { y0[h][j] = 0.f; y1[h][j] = 0.f; }

    // ---- phase 2: gather-accumulate (coalesced 64B/node lines) ----
    #pragma unroll 4
    for (int k = 0; k < K_N; ++k) {
        const int si = sidx_s[m][k];                       // broadcast across q
        const f16x8 xa = *(const f16x8*)&xbase[(size_t)si * D_N];
        const f16x8 xb = *(const f16x8*)&xbase[(size_t)si * D_N + 32];
        const float4 c = *(const float4*)&coefs_s[k][m][0];
        const float ch[H_N] = { c.x, c.y, c.z, c.w };
        #pragma unroll
        for (int h = 0; h < H_N; ++h)
            #pragma unroll
            for (int j = 0; j < 8; ++j) {
                y0[h][j] = fmaf(ch[h], (float)xa[j], y0[h][j]);   // v_fma_mix
                y1[h][j] = fmaf(ch[h], (float)xb[j], y1[h][j]);
            }
    }

    // convert y -> fp16 A-fragments (already in frag lane layout)
    f16x8 af0[H_N], af1[H_N];
    #pragma unroll
    for (int h = 0; h < H_N; ++h)
        #pragma unroll
        for (int j = 0; j < 8; ++j) {
            af0[h][j] = (_Float16)y0[h][j];
            af1[h][j] = (_Float16)y1[h][j];
        }

    // ---- phase 3: C_partial = sum_h sum_{kc in slice} A(h,kc) . Wt(h,kc) ----
    f32x4 acc[8];
    #pragma unroll
    for (int n = 0; n < 8; ++n) acc[n] = (f32x4){0.f, 0.f, 0.f, 0.f};

    const _Float16* Wl = Wt + wid * 64 + q * 8;   // + row*256 (+32 for tile1)
    #pragma unroll
    for (int h = 0; h < H_N; ++h) {
        #pragma unroll
        for (int n = 0; n < 8; ++n) {
            const size_t row = (size_t)(h * O_N + n * 16 + m) * D_N;
            const f16x8 b0 = *(const f16x8*)&Wl[row];
            const f16x8 b1 = *(const f16x8*)&Wl[row + 32];
            acc[n] = __builtin_amdgcn_mfma_f32_16x16x32_f16(af0[h], b0, acc[n], 0, 0, 0);
            acc[n] = __builtin_amdgcn_mfma_f32_16x16x32_f16(af1[h], b1, acc[n], 0, 0, 0);
        }
    }

    // write per-wave partials; C layout: col = lane&15(=m), row(node) = q*4+r
    #pragma unroll
    for (int n = 0; n < 8; ++n)
        #pragma unroll
        for (int r = 0; r < 4; ++r)
            cred[wid][q * 4 + r][n * 16 + m] = acc[n][r];
    __syncthreads();

    // ---- reduce 4 wave-partials + epilogue ----
    {
        const int node = tid >> 4;
        const int cg   = tid & 15;        // 8 cols at cg*8
        float4 s0 = (float4){0.f, 0.f, 0.f, 0.f};
        float4 s1 = (float4){0.f, 0.f, 0.f, 0.f};
        #pragma unroll
        for (int s = 0; s < 4; ++s) {
            const float4 p0 = *(const float4*)&cred[s][node][cg * 8];
            const float4 p1 = *(const float4*)&cred[s][node][cg * 8 + 4];
            s0.x += p0.x; s0.y += p0.y; s0.z += p0.z; s0.w += p0.w;
            s1.x += p1.x; s1.y += p1.y; s1.z += p1.z; s1.w += p1.w;
        }
        float r[8] = { s0.x, s0.y, s0.z, s0.w, s1.x, s1.y, s1.z, s1.w };
        float4 o0, o1;
        float* op[8] = { &o0.x, &o0.y, &o0.z, &o0.w, &o1.x, &o1.y, &o1.z, &o1.w };
        #pragma unroll
        for (int j = 0; j < 8; ++j) {
            const int col = cg * 8 + j;
            const float bb = b[col] + b[O_N + col] + b[2 * O_N + col] + b[3 * O_N + col];
            *op[j] = fmaxf(0.25f * (r[j] + bb), 0.f);
        }
        float* dst = &out[(size_t)(v0 + node) * O_N + cg * 8];
        *(float4*)dst = o0;
        *(float4*)(dst + 4) = o1;
    }
}

extern "C" void kernel_launch(void* const* d_in, const int* in_sizes, int n_in,
                              void* d_out, int out_size, void* d_ws, size_t ws_size,
                              hipStream_t stream) {
    const float* x      = (const float*)d_in[0];
    const float* W      = (const float*)d_in[1];
    const float* a      = (const float*)d_in[2];
    const float* b      = (const float*)d_in[3];
    const int*   adj    = (const int*)d_in[4];
    const int*   mask_p = (const int*)d_in[5];
    float*       out    = (float*)d_out;

    // ws layout (bytes)
    char* p = (char*)d_ws;
    float*    attn4 = (float*)p;                     //    320,000
    _Float16* xh    = (_Float16*)(p + 320000);       // 10,240,000
    _Float16* Wt    = (_Float16*)(p + 10560000);     //    262,144
    float*    wt    = (float*)(p + 10822144);        //      4,096  (~10.8MB)

    prep_w_kernel<<<(H_N * O_N * D_N) / 256, 256, 0, stream>>>(W, Wt);
    wtilde_kernel<<<H_N, 256, 0, stream>>>(W, a, wt);
    xsplit_attn_kernel<<<V_N / 4, 256, 0, stream>>>(x, wt, xh, attn4);
    gat_kernel<<<V_N / TM, 256, 0, stream>>>(xh, attn4, Wt, b, adj, mask_p, out);
}

// Round 6
// 128.521 us; speedup vs baseline: 1.4264x; 1.1642x over previous
//
#include <hip/hip_runtime.h>

// AdjGAT: V=20000, D=256, K=16, O=128, H=4.
// Math: attn[h,v] = x[v].(W_h a_h);  out[v] = relu( (1/H)[ sum_h (sum_k c_hk x[nbr_k]).W_h + sum_h b_h ] )
// Gather x rows (head-independent indices); aggregate y = sum_k c*x, then y.W via MFMA.
// Pipeline:
//   K0a prep_w:  W fp32 [h][d][o] -> Wt fp16 in EXACT MFMA B-fragment order:
//                Wt[((h*8+s)*8+nt)*64+lane][8] holds W[d=s*32+(lane>>4)*8+j][o=nt*16+(lane&15)]
//                -> phase3 B loads are dense 1KB per fragment.
//   K0b wtilde:  wt[h][d] = sum_o W[h][d][o]*a[h][o]   (fp32, tiny)
//   K0c xsplit:  xh = fp16(x); attn4[v][h] = x[v].wt[h] (fused)
//   K1  gat:     16 nodes/block, 4 waves.
//                P1: softmax coefs (width-16 shuffles).
//                P2: wave w gathers channel slice [w*64,w*64+64) for all 16 nodes
//                    (coalesced 64B/node segments), y in fp32 regs (A-frag lane
//                    layout), converts to fp16 and writes LDS in A-FRAGMENT ORDER
//                    (lane-contiguous, conflict-free).
//                P3: wave w computes output cols [w*32,w*32+32) over FULL K
//                    (4 heads x 8 slices): ds_read_b128 A + dense global B + 64
//                    MFMAs; no cross-wave reduction. Epilogue: mean+bias+relu.
// ws: attn4 0.32MB | xh 10.24MB | Wt 0.26MB | wt 4KB  (~10.8MB)

#define V_N 20000
#define D_N 256
#define K_N 16
#define O_N 128
#define H_N 4
#define NEG_INF -1e9f
#define TM 16            // nodes per block; V = 1250 * 16

typedef _Float16 f16x8 __attribute__((ext_vector_type(8)));
typedef _Float16 f16x4 __attribute__((ext_vector_type(4)));
typedef float    f32x4 __attribute__((ext_vector_type(4)));

// ---------------- K0a: W -> Wt fp16, MFMA B-fragment order ----------------
__global__ __launch_bounds__(256) void prep_w_kernel(
    const float* __restrict__ W, _Float16* __restrict__ Wt)
{
    const int idx  = blockIdx.x * 256 + threadIdx.x;  // 16384 fragment-lane slots
    const int lane = idx & 63;
    const int nt   = (idx >> 6) & 7;    // col tile (16 cols)
    const int s    = (idx >> 9) & 7;    // k slice (32 chans)
    const int h    = idx >> 12;
    const int o    = nt * 16 + (lane & 15);
    const int d0   = s * 32 + (lane >> 4) * 8;
    f16x8 v;
    #pragma unroll
    for (int j = 0; j < 8; ++j)
        v[j] = (_Float16)W[((size_t)h * D_N + d0 + j) * O_N + o];
    *(f16x8*)&Wt[(size_t)idx * 8] = v;
}

// ---------------- K0b: wt[h][d] = sum_o W[h][d][o] * a[h][o] ----------------
__global__ __launch_bounds__(256) void wtilde_kernel(
    const float* __restrict__ W, const float* __restrict__ a,
    float* __restrict__ wt)
{
    const int h = blockIdx.x;
    const int d = threadIdx.x;
    const float* Wrow = W + ((size_t)h * D_N + d) * O_N;
    const float* ah   = a + h * O_N;
    float s = 0.f;
    #pragma unroll
    for (int o = 0; o < O_N; o += 4) {
        const float4 wv = *(const float4*)&Wrow[o];
        const float4 av = *(const float4*)&ah[o];
        s = fmaf(wv.x, av.x, s); s = fmaf(wv.y, av.y, s);
        s = fmaf(wv.z, av.z, s); s = fmaf(wv.w, av.w, s);
    }
    wt[h * D_N + d] = s;
}

// ---------------- K0c: x -> fp16 copy + fused attn logits ----------------
__global__ __launch_bounds__(256) void xsplit_attn_kernel(
    const float* __restrict__ x, const float* __restrict__ wt,
    _Float16* __restrict__ xh, float* __restrict__ attn4)
{
    const int wid  = threadIdx.x >> 6;
    const int lane = threadIdx.x & 63;
    const int v    = blockIdx.x * 4 + wid;

    const float4 p = *(const float4*)&x[(size_t)v * D_N + lane * 4];
    f16x4 hv = { (_Float16)p.x, (_Float16)p.y, (_Float16)p.z, (_Float16)p.w };
    *(f16x4*)&xh[(size_t)v * D_N + lane * 4] = hv;

    float s[H_N];
    #pragma unroll
    for (int h = 0; h < H_N; ++h) {
        const float4 w = *(const float4*)&wt[h * D_N + lane * 4];
        float t = fmaf(p.x, w.x, 0.f);
        t = fmaf(p.y, w.y, t); t = fmaf(p.z, w.z, t); t = fmaf(p.w, w.w, t);
        s[h] = t;
    }
    #pragma unroll
    for (int h = 0; h < H_N; ++h)
        #pragma unroll
        for (int dd = 32; dd >= 1; dd >>= 1)
            s[h] += __shfl_xor(s[h], dd);
    if (lane == 0)
        *(float4*)&attn4[(size_t)v * 4] = make_float4(s[0], s[1], s[2], s[3]);
}

// ---------------- K1: fused softmax + gather + full-K fp16 MFMA -------------
__global__ __launch_bounds__(256, 4) void gat_kernel(
    const _Float16* __restrict__ xh, const float* __restrict__ attn4,
    const _Float16* __restrict__ Wt, const float* __restrict__ b,
    const int* __restrict__ adj, const int* __restrict__ mask_p,
    float* __restrict__ out)
{
    const int v0  = blockIdx.x * TM;
    const int tid = threadIdx.x;

    __shared__ int      sidx_s[TM][17];          // +1 pad
    __shared__ float    coefs_s[K_N][17][H_N];   // [k][node(+pad)][h]
    __shared__ _Float16 yl[H_N * 8 * 64 * 8];    // A-fragment order: 32KB

    // ---- P1: softmax coefs, thread = (node, k) ----
    {
        const int node = tid >> 4;
        const int k    = tid & 15;
        const int mask = mask_p[0];
        const int idx  = adj[(v0 + node) * K_N + k];
        const bool pad = (idx >= mask);
        const int safe = pad ? 0 : idx;
        const float4 av = *(const float4*)&attn4[(size_t)safe * 4];
        const float lg[H_N] = { pad ? NEG_INF : av.x, pad ? NEG_INF : av.y,
                                pad ? NEG_INF : av.z, pad ? NEG_INF : av.w };
        float c[H_N];
        #pragma unroll
        for (int h = 0; h < H_N; ++h) {
            float m = lg[h];
            #pragma unroll
            for (int s = 8; s >= 1; s >>= 1)
                m = fmaxf(m, __shfl_xor(m, s, 16));
            const float e = pad ? 0.f : __expf(lg[h] - m);
            float sum = e;
            #pragma unroll
            for (int s = 8; s >= 1; s >>= 1)
                sum += __shfl_xor(sum, s, 16);
            // pad coef 0 == ref (exp(-1e9-m)==0); all-pad row -> y=0 -> relu(bbar)
            c[h] = pad ? 0.f : e / sum;
        }
        *(float4*)&coefs_s[k][node][0] = make_float4(c[0], c[1], c[2], c[3]);
        sidx_s[node][k] = safe;
    }
    __syncthreads();

    const int wid  = tid >> 6;
    const int lane = tid & 63;
    const int m    = lane & 15;           // node / A-frag row / C col
    const int q    = lane >> 4;           // channel group / C row group

    // ---- P2: gather-accumulate channel slice [wid*64, wid*64+64) ----
    {
        const _Float16* xbase = xh + wid * 64 + q * 8;
        float y0[H_N][8], y1[H_N][8];
        #pragma unroll
        for (int h = 0; h < H_N; ++h)
            #pragma unroll
            for (int j = 0; j < 8; ++j) { y0[h][j] = 0.f; y1[h][j] = 0.f; }

        #pragma unroll 4
        for (int k = 0; k < K_N; ++k) {
            const int si = sidx_s[m][k];
            const f16x8 xa = *(const f16x8*)&xbase[(size_t)si * D_N];
            const f16x8 xb = *(const f16x8*)&xbase[(size_t)si * D_N + 32];
            const float4 c = *(const float4*)&coefs_s[k][m][0];
            const float ch[H_N] = { c.x, c.y, c.z, c.w };
            #pragma unroll
            for (int h = 0; h < H_N; ++h)
                #pragma unroll
                for (int j = 0; j < 8; ++j) {
                    y0[h][j] = fmaf(ch[h], (float)xa[j], y0[h][j]);
                    y1[h][j] = fmaf(ch[h], (float)xb[j], y1[h][j]);
                }
        }
        // write y as fp16 A-fragments: slice s0 = wid*2 (+1); lane-contiguous.
        #pragma unroll
        for (int h = 0; h < H_N; ++h) {
            f16x8 v0, v1;
            #pragma unroll
            for (int j = 0; j < 8; ++j) {
                v0[j] = (_Float16)y0[h][j];
                v1[j] = (_Float16)y1[h][j];
            }
            *(f16x8*)&yl[(((h * 8 + wid * 2 + 0) * 64) + lane) * 8] = v0;
            *(f16x8*)&yl[(((h * 8 + wid * 2 + 1) * 64) + lane) * 8] = v1;
        }
    }
    __syncthreads();

    // ---- P3: cols [wid*32, wid*32+32) over full K (4h x 8 slices) ----
    f32x4 acc0 = (f32x4){0.f, 0.f, 0.f, 0.f};
    f32x4 acc1 = (f32x4){0.f, 0.f, 0.f, 0.f};
    {
        const _Float16* Wb = Wt + (size_t)lane * 8;
        #pragma unroll
        for (int h = 0; h < H_N; ++h) {
            #pragma unroll
            for (int s = 0; s < 8; ++s) {
                const f16x8 af = *(const f16x8*)&yl[((h * 8 + s) * 64 + lane) * 8];
                const size_t fb = (size_t)((h * 8 + s) * 8 + wid * 2) * 512;
                const f16x8 b0 = *(const f16x8*)&Wb[fb];
                const f16x8 b1 = *(const f16x8*)&Wb[fb + 512];
                acc0 = __builtin_amdgcn_mfma_f32_16x16x32_f16(af, b0, acc0, 0, 0, 0);
                acc1 = __builtin_amdgcn_mfma_f32_16x16x32_f16(af, b1, acc1, 0, 0, 0);
            }
        }
    }

    // ---- epilogue: mean heads + mean bias + relu; C: col=m, row=q*4+r ----
    #pragma unroll
    for (int nt = 0; nt < 2; ++nt) {
        const f32x4 acc = nt ? acc1 : acc0;
        const int col = (wid * 2 + nt) * 16 + m;
        const float bb = b[col] + b[O_N + col] + b[2 * O_N + col] + b[3 * O_N + col];
        #pragma unroll
        for (int r = 0; r < 4; ++r) {
            const int node = q * 4 + r;
            out[(size_t)(v0 + node) * O_N + col] = fmaxf(0.25f * (acc[r] + bb), 0.f);
        }
    }
}

extern "C" void kernel_launch(void* const* d_in, const int* in_sizes, int n_in,
                              void* d_out, int out_size, void* d_ws, size_t ws_size,
                              hipStream_t stream) {
    const float* x      = (const float*)d_in[0];
    const float* W      = (const float*)d_in[1];
    const float* a      = (const float*)d_in[2];
    const float* b      = (const float*)d_in[3];
    const int*   adj    = (const int*)d_in[4];
    const int*   mask_p = (const int*)d_in[5];
    float*       out    = (float*)d_out;

    // ws layout (bytes)
    char* p = (char*)d_ws;
    float*    attn4 = (float*)p;                     //    320,000
    _Float16* xh    = (_Float16*)(p + 320000);       // 10,240,000
    _Float16* Wt    = (_Float16*)(p + 10560000);     //    262,144
    float*    wt    = (float*)(p + 10822144);        //      4,096  (~10.8MB)

    prep_w_kernel<<<(H_N * O_N * D_N) / (256 * 8), 256, 0, stream>>>(W, Wt);
    wtilde_kernel<<<H_N, 256, 0, stream>>>(W, a, wt);
    xsplit_attn_kernel<<<V_N / 4, 256, 0, stream>>>(x, wt, xh, attn4);
    gat_kernel<<<V_N / TM, 256, 0, stream>>>(xh, attn4, Wt, b, adj, mask_p, out);
}